// Round 1
// baseline (318.664 us; speedup 1.0000x reference)
//
#include <hip/hip_runtime.h>
#include <hip/hip_bf16.h>

// WindowAttention: WINDOW=(2,8,8) -> N=128 tokens, B_=1024 windows, C=192, H=6, hd=32, nW=64.
// Pipeline: bias gather -> QKV bf16-MFMA GEMM -> per-(b,h) fused attention -> proj GEMM.
// ws layout (bytes): [0, 393216) bias f32 [6][128][128]
//                    [393216, +50331648) q bf16 [b][h][n][d]   (pre-scaled by hd^-0.5)
//                    [.., +50331648)     k bf16 [b][h][n][d]
//                    [.., +50331648)     v bf16 [b][h][d][n]   (transposed for PV B-operand)
// total ws = 151,388,160 B. d_out doubles as fp32 scratch for the attention output.

typedef float f32x4 __attribute__((ext_vector_type(4)));
typedef short short8 __attribute__((ext_vector_type(8)));
typedef short short4e __attribute__((ext_vector_type(4)));

#define SCALE 0.17677669529663687f

static __device__ __forceinline__ short f2bf(float f) {
  __hip_bfloat16 h = __float2bfloat16(f);
  return __builtin_bit_cast(short, h);
}

// ---------------- kernel 0: relative-position bias gather ----------------
__global__ __launch_bounds__(256) void bias_kernel(const int* __restrict__ rel,
                                                   const float* __restrict__ table,
                                                   float* __restrict__ bias) {
  int t = blockIdx.x * 256 + threadIdx.x;  // 0..16383 (n*128+m)
  int idx = rel[t];
#pragma unroll
  for (int h = 0; h < 6; ++h) bias[h * 16384 + t] = table[idx * 6 + h];
}

// ---------------- kernel 1: QKV projection (x @ qkv_w^T) ----------------
__global__ __launch_bounds__(256) void qkv_kernel(const float* __restrict__ x,
                                                  const float* __restrict__ w,
                                                  short* __restrict__ qb,
                                                  short* __restrict__ kb,
                                                  short* __restrict__ vb) {
  __shared__ short xt[128][200];  // padded: stride 400B -> 2-way bank alias only
  __shared__ short wt[64][200];
  int b = blockIdx.x, tid = threadIdx.x;
  const float4* xr = (const float4*)(x + (size_t)b * 128 * 192);
  for (int s = tid; s < 128 * 48; s += 256) {
    float4 f = xr[s];
    int r = s / 48, c = s % 48;
    short4e o4; o4[0] = f2bf(f.x); o4[1] = f2bf(f.y); o4[2] = f2bf(f.z); o4[3] = f2bf(f.w);
    *(short4e*)&xt[r][c * 4] = o4;
  }
  int wave = tid >> 6, lane = tid & 63;
  int lr = lane & 15, lkb = (lane >> 4) * 8, r4 = (lane >> 4) * 4;
  int rowbase = wave * 32;
  for (int ch = 0; ch < 9; ++ch) {  // 9 x 64 output columns
    __syncthreads();
    for (int s = tid; s < 64 * 48; s += 256) {
      int r = s / 48, c = s % 48;
      float4 f = ((const float4*)w)[(ch * 64 + r) * 48 + c];
      short4e o4; o4[0] = f2bf(f.x); o4[1] = f2bf(f.y); o4[2] = f2bf(f.z); o4[3] = f2bf(f.w);
      *(short4e*)&wt[r][c * 4] = o4;
    }
    __syncthreads();
    f32x4 acc[2][4];
#pragma unroll
    for (int i = 0; i < 2; ++i)
#pragma unroll
      for (int j = 0; j < 4; ++j) acc[i][j] = f32x4{0.f, 0.f, 0.f, 0.f};
#pragma unroll
    for (int ks = 0; ks < 6; ++ks) {
      short8 a0 = *(const short8*)&xt[rowbase + lr][ks * 32 + lkb];
      short8 a1 = *(const short8*)&xt[rowbase + 16 + lr][ks * 32 + lkb];
#pragma unroll
      for (int cf = 0; cf < 4; ++cf) {
        short8 bb = *(const short8*)&wt[cf * 16 + lr][ks * 32 + lkb];
        acc[0][cf] = __builtin_amdgcn_mfma_f32_16x16x32_bf16(a0, bb, acc[0][cf], 0, 0, 0);
        acc[1][cf] = __builtin_amdgcn_mfma_f32_16x16x32_bf16(a1, bb, acc[1][cf], 0, 0, 0);
      }
    }
#pragma unroll
    for (int rf = 0; rf < 2; ++rf)
#pragma unroll
      for (int cf = 0; cf < 4; ++cf) {
        int j = ch * 64 + cf * 16 + lr;
        int which = j / 192, jj = j % 192;
        int h = jj >> 5, d = jj & 31;
        size_t bh = (size_t)b * 6 + h;
#pragma unroll
        for (int rg = 0; rg < 4; ++rg) {
          int tok = rowbase + rf * 16 + r4 + rg;
          float vv = acc[rf][cf][rg];
          if (which == 0)      qb[(bh * 128 + tok) * 32 + d] = f2bf(vv * SCALE);
          else if (which == 1) kb[(bh * 128 + tok) * 32 + d] = f2bf(vv);
          else                 vb[(bh * 32 + d) * 128 + tok] = f2bf(vv);
        }
      }
  }
}

// ---------------- kernel 2: fused attention per (window, head) ----------------
__global__ __launch_bounds__(256) void attn_kernel(const short* __restrict__ qb,
                                                   const short* __restrict__ kb,
                                                   const short* __restrict__ vb,
                                                   const float* __restrict__ bias,
                                                   const float* __restrict__ mask,
                                                   float* __restrict__ aout) {
  __shared__ short p_lds[128][136];  // P transpose staging, padded
  int bh = blockIdx.x;
  int b = bh / 6, h = bh % 6;
  const short* qt = qb + (size_t)bh * 128 * 32;
  const short* kt = kb + (size_t)bh * 128 * 32;
  const short* vt = vb + (size_t)bh * 32 * 128;
  const float* bs = bias + (size_t)h * 16384;
  const float* mk = mask + (size_t)(b & 63) * 16384;
  int tid = threadIdx.x, wave = tid >> 6, lane = tid & 63;
  int lr = lane & 15, lkb = (lane >> 4) * 8, r4 = (lane >> 4) * 4;
  int rowbase = wave * 32;  // each wave owns 32 q-rows

  // S = q k^T  (K=32 -> single MFMA k-step), 2 row-frags x 8 col-frags
  f32x4 s[2][8];
  {
    short8 a0 = *(const short8*)&qt[(rowbase + lr) * 32 + lkb];
    short8 a1 = *(const short8*)&qt[(rowbase + 16 + lr) * 32 + lkb];
#pragma unroll
    for (int cf = 0; cf < 8; ++cf) {
      short8 bb = *(const short8*)&kt[(cf * 16 + lr) * 32 + lkb];
      f32x4 z = {0.f, 0.f, 0.f, 0.f};
      s[0][cf] = __builtin_amdgcn_mfma_f32_16x16x32_bf16(a0, bb, z, 0, 0, 0);
      s[1][cf] = __builtin_amdgcn_mfma_f32_16x16x32_bf16(a1, bb, z, 0, 0, 0);
    }
  }
  // bias + mask + softmax (each row lives in the 16 lanes sharing lane>>4)
#pragma unroll
  for (int rf = 0; rf < 2; ++rf) {
#pragma unroll
    for (int rg = 0; rg < 4; ++rg) {
      int row = rowbase + rf * 16 + r4 + rg;
      float vals[8];
      float mx = -1e30f;
#pragma unroll
      for (int cf = 0; cf < 8; ++cf) {
        int col = cf * 16 + lr;
        float v = s[rf][cf][rg] + bs[row * 128 + col] + mk[row * 128 + col];
        vals[cf] = v;
        mx = fmaxf(mx, v);
      }
#pragma unroll
      for (int o = 1; o < 16; o <<= 1) mx = fmaxf(mx, __shfl_xor(mx, o));
      float sum = 0.f;
#pragma unroll
      for (int cf = 0; cf < 8; ++cf) { vals[cf] = __expf(vals[cf] - mx); sum += vals[cf]; }
#pragma unroll
      for (int o = 1; o < 16; o <<= 1) sum += __shfl_xor(sum, o);
      float inv = 1.f / sum;
#pragma unroll
      for (int cf = 0; cf < 8; ++cf) p_lds[row][cf * 16 + lr] = f2bf(vals[cf] * inv);
    }
  }
  __syncthreads();
  // O = P @ V : K=128 -> 4 k-steps; V is pre-transposed [d][token]
  f32x4 o[2][2];
#pragma unroll
  for (int i = 0; i < 2; ++i)
#pragma unroll
    for (int j = 0; j < 2; ++j) o[i][j] = f32x4{0.f, 0.f, 0.f, 0.f};
#pragma unroll
  for (int ks = 0; ks < 4; ++ks) {
    short8 pa0 = *(const short8*)&p_lds[rowbase + lr][ks * 32 + lkb];
    short8 pa1 = *(const short8*)&p_lds[rowbase + 16 + lr][ks * 32 + lkb];
    short8 b0 = *(const short8*)&vt[lr * 128 + ks * 32 + lkb];
    short8 b1 = *(const short8*)&vt[(16 + lr) * 128 + ks * 32 + lkb];
    o[0][0] = __builtin_amdgcn_mfma_f32_16x16x32_bf16(pa0, b0, o[0][0], 0, 0, 0);
    o[0][1] = __builtin_amdgcn_mfma_f32_16x16x32_bf16(pa0, b1, o[0][1], 0, 0, 0);
    o[1][0] = __builtin_amdgcn_mfma_f32_16x16x32_bf16(pa1, b0, o[1][0], 0, 0, 0);
    o[1][1] = __builtin_amdgcn_mfma_f32_16x16x32_bf16(pa1, b1, o[1][1], 0, 0, 0);
  }
#pragma unroll
  for (int rf = 0; rf < 2; ++rf)
#pragma unroll
    for (int cf = 0; cf < 2; ++cf)
#pragma unroll
      for (int rg = 0; rg < 4; ++rg) {
        int tok = rowbase + rf * 16 + r4 + rg;
        int d = cf * 16 + lr;
        aout[((size_t)b * 128 + tok) * 192 + h * 32 + d] = o[rf][cf][rg];
      }
}

// ---------------- kernel 3: output projection (in-place on d_out) ----------------
__global__ __launch_bounds__(256) void proj_kernel(const float* __restrict__ ain,
                                                   const float* __restrict__ w,
                                                   const float* __restrict__ pb,
                                                   float* __restrict__ out) {
  __shared__ short at[128][200];
  __shared__ short wt[64][200];
  int b = blockIdx.x, tid = threadIdx.x;
  const float4* ar = (const float4*)(ain + (size_t)b * 128 * 192);
  for (int s = tid; s < 128 * 48; s += 256) {
    float4 f = ar[s];
    int r = s / 48, c = s % 48;
    short4e o4; o4[0] = f2bf(f.x); o4[1] = f2bf(f.y); o4[2] = f2bf(f.z); o4[3] = f2bf(f.w);
    *(short4e*)&at[r][c * 4] = o4;
  }
  int wave = tid >> 6, lane = tid & 63;
  int lr = lane & 15, lkb = (lane >> 4) * 8, r4 = (lane >> 4) * 4;
  int rowbase = wave * 32;
  for (int ch = 0; ch < 3; ++ch) {
    __syncthreads();
    for (int s = tid; s < 64 * 48; s += 256) {
      int r = s / 48, c = s % 48;
      float4 f = ((const float4*)w)[(ch * 64 + r) * 48 + c];
      short4e o4; o4[0] = f2bf(f.x); o4[1] = f2bf(f.y); o4[2] = f2bf(f.z); o4[3] = f2bf(f.w);
      *(short4e*)&wt[r][c * 4] = o4;
    }
    __syncthreads();
    f32x4 acc[2][4];
#pragma unroll
    for (int i = 0; i < 2; ++i)
#pragma unroll
      for (int j = 0; j < 4; ++j) acc[i][j] = f32x4{0.f, 0.f, 0.f, 0.f};
#pragma unroll
    for (int ks = 0; ks < 6; ++ks) {
      short8 a0 = *(const short8*)&at[rowbase + lr][ks * 32 + lkb];
      short8 a1 = *(const short8*)&at[rowbase + 16 + lr][ks * 32 + lkb];
#pragma unroll
      for (int cf = 0; cf < 4; ++cf) {
        short8 bb = *(const short8*)&wt[cf * 16 + lr][ks * 32 + lkb];
        acc[0][cf] = __builtin_amdgcn_mfma_f32_16x16x32_bf16(a0, bb, acc[0][cf], 0, 0, 0);
        acc[1][cf] = __builtin_amdgcn_mfma_f32_16x16x32_bf16(a1, bb, acc[1][cf], 0, 0, 0);
      }
    }
#pragma unroll
    for (int rf = 0; rf < 2; ++rf)
#pragma unroll
      for (int cf = 0; cf < 4; ++cf) {
        int j = ch * 64 + cf * 16 + lr;
        float bj = pb[j];
#pragma unroll
        for (int rg = 0; rg < 4; ++rg) {
          int tok = rowbase + rf * 16 + r4 + rg;
          out[((size_t)b * 128 + tok) * 192 + j] = acc[rf][cf][rg] + bj;
        }
      }
  }
}

extern "C" void kernel_launch(void* const* d_in, const int* in_sizes, int n_in,
                              void* d_out, int out_size, void* d_ws, size_t ws_size,
                              hipStream_t stream) {
  const float* x      = (const float*)d_in[0];
  const float* mask   = (const float*)d_in[1];
  const float* qkv_w  = (const float*)d_in[2];
  const float* proj_w = (const float*)d_in[3];
  const float* proj_b = (const float*)d_in[4];
  const float* table  = (const float*)d_in[5];
  const int*   rel    = (const int*)d_in[6];
  char* ws = (char*)d_ws;
  float* bias = (float*)ws;
  short* qb = (short*)(ws + 393216);
  short* kb = (short*)(ws + 393216 + 50331648);
  short* vb = (short*)(ws + 393216 + 2 * (size_t)50331648);
  float* out = (float*)d_out;

  bias_kernel<<<64, 256, 0, stream>>>(rel, table, bias);
  qkv_kernel<<<1024, 256, 0, stream>>>(x, qkv_w, qb, kb, vb);
  attn_kernel<<<6144, 256, 0, stream>>>(qb, kb, vb, bias, mask, out);
  proj_kernel<<<1024, 256, 0, stream>>>(out, proj_w, proj_b, out);
}

// Round 2
// 193.812 us; speedup vs baseline: 1.6442x; 1.6442x over previous
//
#include <hip/hip_runtime.h>
#include <hip/hip_bf16.h>

// WindowAttention v2: prep(Wconv+bias) -> qkv (swizzled LDS, dbuf W chunks) -> attn -> proj.
// N=128 tokens, B_=1024 windows, C=192, H=6, hd=32.
// ws: bias f32 [6][128][128] | wbf bf16[576][192] | pwbf bf16[192][192] |
//     q bf16 [b][h][n][d] (pre-scaled) | k same | v bf16 [b][h][d][n] |
//     (optional) attn-out bf16 [b][n][192]

typedef float f32x4 __attribute__((ext_vector_type(4)));
typedef short short8 __attribute__((ext_vector_type(8)));
typedef short short4e __attribute__((ext_vector_type(4)));

#define SCALE 0.17677669529663687f

static __device__ __forceinline__ short f2bf(float f) {
  __hip_bfloat16 h = __float2bfloat16(f);
  return __builtin_bit_cast(short, h);
}
static __device__ __forceinline__ f32x4 mfma16(short8 a, short8 b, f32x4 c) {
  return __builtin_amdgcn_mfma_f32_16x16x32_bf16(a, b, c, 0, 0, 0);
}

// ---------------- prep: convert qkv_w/proj_w to bf16 + bias gather ----------------
__global__ __launch_bounds__(256) void prep_kernel(const float* __restrict__ qkvw,
                                                   const float* __restrict__ projw,
                                                   const int* __restrict__ rel,
                                                   const float* __restrict__ table,
                                                   short* __restrict__ wbf,
                                                   short* __restrict__ pwbf,
                                                   float* __restrict__ bias) {
  int blk = blockIdx.x;
  if (blk < 144) {
    int t = blk * 256 + threadIdx.x;  // float4 index 0..36863
    const int NQ = 27648;             // 576*192/4
    float4 f; short* dst;
    if (t < NQ) { f = ((const float4*)qkvw)[t]; dst = wbf + t * 4; }
    else        { f = ((const float4*)projw)[t - NQ]; dst = pwbf + (t - NQ) * 4; }
    short4e o; o[0] = f2bf(f.x); o[1] = f2bf(f.y); o[2] = f2bf(f.z); o[3] = f2bf(f.w);
    *(short4e*)dst = o;
  } else {
    int t = (blk - 144) * 256 + threadIdx.x;  // 0..16383
    int idx = rel[t];
#pragma unroll
    for (int h = 0; h < 6; ++h) bias[h * 16384 + t] = table[idx * 6 + h];
  }
}

// ---------------- qkv: x[128][192] @ W^T, W streamed in 32-col bf16 chunks ----------------
__global__ __launch_bounds__(256, 2) void qkv_kernel(const float* __restrict__ x,
                                                     const short* __restrict__ wbf,
                                                     short* __restrict__ qb,
                                                     short* __restrict__ kb,
                                                     short* __restrict__ vb) {
  __shared__ short xt[24576];    // [128][192] bf16, XOR-swizzled (byte ^= (row&7)<<4)
  __shared__ short wt[2][6144];  // [32][192] bf16 double buffer, same swizzle
  const int b = blockIdx.x, tid = threadIdx.x;
  const int wave = tid >> 6, lane = tid & 63;
  const int lr = lane & 15, g = lane >> 4;
  const int g16 = g * 16, r4 = g * 4;
  const int rowbase = wave * 32;
  const int xorkey = (lr & 7) << 4;
  char* xtb = (char*)xt;
  char* wtb = (char*)wt;

  // W-chunk staging offsets: 768 16B granules, 3 per thread
  int wsoff[3], wdoff[3];
#pragma unroll
  for (int i = 0; i < 3; ++i) {
    int idx8 = i * 256 + tid;
    int r = idx8 / 24, c = idx8 - r * 24;
    wsoff[i] = idx8 * 8;  // shorts
    wdoff[i] = r * 384 + ((c * 16) ^ ((r & 7) << 4));
  }
  short8 wreg[3];
#pragma unroll
  for (int i = 0; i < 3; ++i) wreg[i] = *(const short8*)(wbf + wsoff[i]);  // chunk 0

  // stage x tile once: f32 -> bf16, swizzled
  const float4* xr = (const float4*)(x + (size_t)b * 24576);
  for (int s = tid; s < 6144; s += 256) {
    float4 f = xr[s];
    int r = s / 48, c8 = s - r * 48;
    int off = r * 384 + ((c8 * 8) ^ ((r & 7) << 4));
    short4e o; o[0] = f2bf(f.x); o[1] = f2bf(f.y); o[2] = f2bf(f.z); o[3] = f2bf(f.w);
    *(short4e*)(xtb + off) = o;
  }
#pragma unroll
  for (int i = 0; i < 3; ++i) *(short8*)(wtb + wdoff[i]) = wreg[i];
  __syncthreads();

  const int rA0 = (rowbase + lr) * 384, rA1 = rA0 + 16 * 384;
  const int wB0 = lr * 384, wB1 = wB0 + 16 * 384;

  for (int ch = 0; ch < 18; ++ch) {
    if (ch < 17) {
#pragma unroll
      for (int i = 0; i < 3; ++i)
        wreg[i] = *(const short8*)(wbf + (ch + 1) * 6144 + wsoff[i]);
    }
    const char* wbuf = wtb + (ch & 1) * 12288;
    f32x4 acc[2][2];
    acc[0][0] = acc[0][1] = acc[1][0] = acc[1][1] = f32x4{0.f, 0.f, 0.f, 0.f};
    const bool isv = (ch >= 12);
#pragma unroll
    for (int ks = 0; ks < 6; ++ks) {
      int cx = (ks * 64 + g16) ^ xorkey;
      short8 xa0 = *(const short8*)(xtb + rA0 + cx);
      short8 xa1 = *(const short8*)(xtb + rA1 + cx);
      short8 wf0 = *(const short8*)(wbuf + wB0 + cx);
      short8 wf1 = *(const short8*)(wbuf + wB1 + cx);
      if (!isv) {  // D[tok][j]
        acc[0][0] = mfma16(xa0, wf0, acc[0][0]);
        acc[0][1] = mfma16(xa0, wf1, acc[0][1]);
        acc[1][0] = mfma16(xa1, wf0, acc[1][0]);
        acc[1][1] = mfma16(xa1, wf1, acc[1][1]);
      } else {     // D[j][tok] -> v^T stores lane-contiguous
        acc[0][0] = mfma16(wf0, xa0, acc[0][0]);
        acc[0][1] = mfma16(wf0, xa1, acc[0][1]);
        acc[1][0] = mfma16(wf1, xa0, acc[1][0]);
        acc[1][1] = mfma16(wf1, xa1, acc[1][1]);
      }
    }
    if (!isv) {
      int h = (ch < 6) ? ch : ch - 6;
      short* dst = (ch < 6) ? qb : kb;
      float sc = (ch < 6) ? SCALE : 1.0f;
      size_t base = ((size_t)b * 6 + h) * 4096;
#pragma unroll
      for (int rf = 0; rf < 2; ++rf)
#pragma unroll
        for (int cf = 0; cf < 2; ++cf) {
          int d = cf * 16 + lr;
#pragma unroll
          for (int rg = 0; rg < 4; ++rg) {
            int tok = rowbase + rf * 16 + r4 + rg;
            dst[base + (size_t)tok * 32 + d] = f2bf(acc[rf][cf][rg] * sc);
          }
        }
    } else {
      int h = ch - 12;
      size_t base = ((size_t)b * 6 + h) * 4096;
#pragma unroll
      for (int jf = 0; jf < 2; ++jf)
#pragma unroll
        for (int tf = 0; tf < 2; ++tf) {
          int tok = rowbase + tf * 16 + lr;
#pragma unroll
          for (int rg = 0; rg < 4; ++rg) {
            int d = jf * 16 + r4 + rg;
            vb[base + (size_t)d * 128 + tok] = f2bf(acc[jf][tf][rg]);
          }
        }
    }
    if (ch < 17) {
#pragma unroll
      for (int i = 0; i < 3; ++i)
        *(short8*)(wtb + ((ch + 1) & 1) * 12288 + wdoff[i]) = wreg[i];
      __syncthreads();
    }
  }
}

// ---------------- fused attention per (window, head) ----------------
template <bool BF16OUT>
__global__ __launch_bounds__(256) void attn_kernel(const short* __restrict__ qb,
                                                   const short* __restrict__ kb,
                                                   const short* __restrict__ vb,
                                                   const float* __restrict__ bias,
                                                   const float* __restrict__ mask,
                                                   float* __restrict__ aoutf,
                                                   short* __restrict__ aoutb) {
  __shared__ short p_lds[128][136];
  int bh = blockIdx.x;
  int b = bh / 6, h = bh % 6;
  const short* qt = qb + (size_t)bh * 4096;
  const short* kt = kb + (size_t)bh * 4096;
  const short* vt = vb + (size_t)bh * 4096;
  const float* bs = bias + (size_t)h * 16384;
  const float* mk = mask + (size_t)(b & 63) * 16384;
  int tid = threadIdx.x, wave = tid >> 6, lane = tid & 63;
  int lr = lane & 15, lkb = (lane >> 4) * 8, r4 = (lane >> 4) * 4;
  int rowbase = wave * 32;

  f32x4 s[2][8];
  {
    short8 a0 = *(const short8*)&qt[(rowbase + lr) * 32 + lkb];
    short8 a1 = *(const short8*)&qt[(rowbase + 16 + lr) * 32 + lkb];
#pragma unroll
    for (int cf = 0; cf < 8; ++cf) {
      short8 bb = *(const short8*)&kt[(cf * 16 + lr) * 32 + lkb];
      f32x4 z = {0.f, 0.f, 0.f, 0.f};
      s[0][cf] = mfma16(a0, bb, z);
      s[1][cf] = mfma16(a1, bb, z);
    }
  }
#pragma unroll
  for (int rf = 0; rf < 2; ++rf) {
#pragma unroll
    for (int rg = 0; rg < 4; ++rg) {
      int row = rowbase + rf * 16 + r4 + rg;
      float vals[8];
      float mx = -1e30f;
#pragma unroll
      for (int cf = 0; cf < 8; ++cf) {
        int col = cf * 16 + lr;
        float v = s[rf][cf][rg] + bs[row * 128 + col] + mk[row * 128 + col];
        vals[cf] = v;
        mx = fmaxf(mx, v);
      }
#pragma unroll
      for (int o = 1; o < 16; o <<= 1) mx = fmaxf(mx, __shfl_xor(mx, o));
      float sum = 0.f;
#pragma unroll
      for (int cf = 0; cf < 8; ++cf) { vals[cf] = __expf(vals[cf] - mx); sum += vals[cf]; }
#pragma unroll
      for (int o = 1; o < 16; o <<= 1) sum += __shfl_xor(sum, o);
      float inv = 1.f / sum;
#pragma unroll
      for (int cf = 0; cf < 8; ++cf) p_lds[row][cf * 16 + lr] = f2bf(vals[cf] * inv);
    }
  }
  __syncthreads();
  f32x4 o[2][2];
#pragma unroll
  for (int i = 0; i < 2; ++i)
#pragma unroll
    for (int j = 0; j < 2; ++j) o[i][j] = f32x4{0.f, 0.f, 0.f, 0.f};
#pragma unroll
  for (int ks = 0; ks < 4; ++ks) {
    short8 pa0 = *(const short8*)&p_lds[rowbase + lr][ks * 32 + lkb];
    short8 pa1 = *(const short8*)&p_lds[rowbase + 16 + lr][ks * 32 + lkb];
    short8 b0 = *(const short8*)&vt[lr * 128 + ks * 32 + lkb];
    short8 b1 = *(const short8*)&vt[(16 + lr) * 128 + ks * 32 + lkb];
    o[0][0] = mfma16(pa0, b0, o[0][0]);
    o[0][1] = mfma16(pa0, b1, o[0][1]);
    o[1][0] = mfma16(pa1, b0, o[1][0]);
    o[1][1] = mfma16(pa1, b1, o[1][1]);
  }
#pragma unroll
  for (int rf = 0; rf < 2; ++rf)
#pragma unroll
    for (int cf = 0; cf < 2; ++cf)
#pragma unroll
      for (int rg = 0; rg < 4; ++rg) {
        int tok = rowbase + rf * 16 + r4 + rg;
        int d = cf * 16 + lr;
        if constexpr (BF16OUT)
          aoutb[((size_t)b * 128 + tok) * 192 + h * 32 + d] = f2bf(o[rf][cf][rg]);
        else
          aoutf[((size_t)b * 128 + tok) * 192 + h * 32 + d] = o[rf][cf][rg];
      }
}

// ---------------- proj: ain[128][192] @ proj_w^T + b ----------------
template <bool BF16IN>
__global__ __launch_bounds__(256, 2) void proj_kernel(const float* __restrict__ ainf,
                                                      const short* __restrict__ ainb,
                                                      const short* __restrict__ pwbf,
                                                      const float* __restrict__ pb,
                                                      float* __restrict__ out) {
  __shared__ short at[24576];
  __shared__ short wt[2][6144];
  const int b = blockIdx.x, tid = threadIdx.x;
  const int wave = tid >> 6, lane = tid & 63;
  const int lr = lane & 15, g = lane >> 4;
  const int g16 = g * 16, r4 = g * 4;
  const int rowbase = wave * 32;
  const int xorkey = (lr & 7) << 4;
  char* atb = (char*)at;
  char* wtb = (char*)wt;

  int wsoff[3], wdoff[3];
#pragma unroll
  for (int i = 0; i < 3; ++i) {
    int idx8 = i * 256 + tid;
    int r = idx8 / 24, c = idx8 - r * 24;
    wsoff[i] = idx8 * 8;
    wdoff[i] = r * 384 + ((c * 16) ^ ((r & 7) << 4));
  }
  short8 wreg[3];
#pragma unroll
  for (int i = 0; i < 3; ++i) wreg[i] = *(const short8*)(pwbf + wsoff[i]);

  if constexpr (BF16IN) {
    const short8* ar = (const short8*)(ainb + (size_t)b * 24576);
#pragma unroll
    for (int i = 0; i < 12; ++i) {
      int idx8 = i * 256 + tid;
      int r = idx8 / 24, c = idx8 - r * 24;
      short8 v = ar[idx8];
      *(short8*)(atb + r * 384 + ((c * 16) ^ ((r & 7) << 4))) = v;
    }
  } else {
    const float4* ar = (const float4*)(ainf + (size_t)b * 24576);
    for (int s = tid; s < 6144; s += 256) {
      float4 f = ar[s];
      int r = s / 48, c8 = s - r * 48;
      int off = r * 384 + ((c8 * 8) ^ ((r & 7) << 4));
      short4e o; o[0] = f2bf(f.x); o[1] = f2bf(f.y); o[2] = f2bf(f.z); o[3] = f2bf(f.w);
      *(short4e*)(atb + off) = o;
    }
  }
#pragma unroll
  for (int i = 0; i < 3; ++i) *(short8*)(wtb + wdoff[i]) = wreg[i];
  __syncthreads();

  const int rA0 = (rowbase + lr) * 384, rA1 = rA0 + 16 * 384;
  const int wB0 = lr * 384, wB1 = wB0 + 16 * 384;

  for (int ch = 0; ch < 6; ++ch) {
    if (ch < 5) {
#pragma unroll
      for (int i = 0; i < 3; ++i)
        wreg[i] = *(const short8*)(pwbf + (ch + 1) * 6144 + wsoff[i]);
    }
    const char* wbuf = wtb + (ch & 1) * 12288;
    f32x4 acc[2][2];
    acc[0][0] = acc[0][1] = acc[1][0] = acc[1][1] = f32x4{0.f, 0.f, 0.f, 0.f};
#pragma unroll
    for (int ks = 0; ks < 6; ++ks) {
      int cx = (ks * 64 + g16) ^ xorkey;
      short8 xa0 = *(const short8*)(atb + rA0 + cx);
      short8 xa1 = *(const short8*)(atb + rA1 + cx);
      short8 wf0 = *(const short8*)(wbuf + wB0 + cx);
      short8 wf1 = *(const short8*)(wbuf + wB1 + cx);
      acc[0][0] = mfma16(xa0, wf0, acc[0][0]);
      acc[0][1] = mfma16(xa0, wf1, acc[0][1]);
      acc[1][0] = mfma16(xa1, wf0, acc[1][0]);
      acc[1][1] = mfma16(xa1, wf1, acc[1][1]);
    }
#pragma unroll
    for (int cf = 0; cf < 2; ++cf) {
      int j = ch * 32 + cf * 16 + lr;
      float bj = pb[j];
#pragma unroll
      for (int rf = 0; rf < 2; ++rf)
#pragma unroll
        for (int rg = 0; rg < 4; ++rg) {
          int tok = rowbase + rf * 16 + r4 + rg;
          out[((size_t)b * 128 + tok) * 192 + j] = acc[rf][cf][rg] + bj;
        }
    }
    if (ch < 5) {
#pragma unroll
      for (int i = 0; i < 3; ++i)
        *(short8*)(wtb + ((ch + 1) & 1) * 12288 + wdoff[i]) = wreg[i];
      __syncthreads();
    }
  }
}

extern "C" void kernel_launch(void* const* d_in, const int* in_sizes, int n_in,
                              void* d_out, int out_size, void* d_ws, size_t ws_size,
                              hipStream_t stream) {
  const float* x      = (const float*)d_in[0];
  const float* mask   = (const float*)d_in[1];
  const float* qkv_w  = (const float*)d_in[2];
  const float* proj_w = (const float*)d_in[3];
  const float* proj_b = (const float*)d_in[4];
  const float* table  = (const float*)d_in[5];
  const int*   rel    = (const int*)d_in[6];
  char* ws = (char*)d_ws;
  size_t o = 0;
  float* bias = (float*)(ws + o); o += 393216;
  short* wbf  = (short*)(ws + o); o += 221184;
  short* pwbf = (short*)(ws + o); o += 73728;
  short* qbp  = (short*)(ws + o); o += 50331648;
  short* kbp  = (short*)(ws + o); o += 50331648;
  short* vbp  = (short*)(ws + o); o += 50331648;
  bool bf16path = (ws_size >= o + 50331648);
  short* aoutb = (short*)(ws + o);
  float* out = (float*)d_out;

  prep_kernel<<<208, 256, 0, stream>>>(qkv_w, proj_w, rel, table, wbf, pwbf, bias);
  qkv_kernel<<<1024, 256, 0, stream>>>(x, wbf, qbp, kbp, vbp);
  if (bf16path) {
    attn_kernel<true><<<6144, 256, 0, stream>>>(qbp, kbp, vbp, bias, mask, nullptr, aoutb);
    proj_kernel<true><<<1024, 256, 0, stream>>>(nullptr, aoutb, pwbf, proj_b, out);
  } else {
    attn_kernel<false><<<6144, 256, 0, stream>>>(qbp, kbp, vbp, bias, mask, out, nullptr);
    proj_kernel<false><<<1024, 256, 0, stream>>>(out, nullptr, pwbf, proj_b, out);
  }
}